// Round 1
// baseline (374.687 us; speedup 1.0000x reference)
//
#include <hip/hip_runtime.h>

// TALayer: deformable 1D conv with fixed integer taps d[j] ∈ {-17..-15,-1..1,15..17}
// out[b,o,t] = sum_{c,j} W[o,c,j] * x[b,c,t+d[j]] (zero-pad OOB) + bias[o]
// B=8, C=O=64, T=65536, K=9.  Strategy: bf16 MFMA GEMM C[64,BT] = W[64,576]*Xg[576,BT].

typedef short bf16x8 __attribute__((ext_vector_type(8)));   // 8 bf16 (4 VGPRs)
typedef float f32x4  __attribute__((ext_vector_type(4)));   // MFMA accumulator

#define T_LEN   65536
#define NT      256           // t-tile per block
#define HALO    17
#define ROWS    292           // 290 used rows (NT + 2*HALO), padded to 292 = 4*73 for staging
#define PITCH   72            // bf16 elements per LDS row (64 + 8 pad -> 144 B, 16B-aligned)
#define NCHUNK  18            // K = 576 = 18 * 32

__device__ __forceinline__ short f2bf(float f) {
    union { float f; unsigned u; } v; v.f = f;
    unsigned u = v.u;
    u += 0x7fffu + ((u >> 16) & 1u);   // round-to-nearest-even
    return (short)(u >> 16);
}

// Pre-arrange weight into MFMA A-fragment order (bf16) in workspace:
// W2[((mt*18 + ch)*64 + lane)*8 + i] = bf16(W[o = mt*16 + (lane&15)][kk = ch*32 + (lane>>4)*8 + i])
// with kk = j*64 + c  ->  j = kk>>6, c = kk&63;  W layout [o][c][j] strides (576, 9, 1).
__global__ void prep_w_kernel(const float* __restrict__ w, short* __restrict__ W2) {
    int idx = blockIdx.x * 256 + threadIdx.x;       // 0 .. 4607
    if (idx >= 4 * NCHUNK * 64) return;
    int lane = idx & 63;
    int chmt = idx >> 6;            // mt*18 + ch
    int ch   = chmt % NCHUNK;
    int mt   = chmt / NCHUNK;
    int o    = mt * 16 + (lane & 15);
    bf16x8 v;
#pragma unroll
    for (int i = 0; i < 8; ++i) {
        int kk = ch * 32 + (lane >> 4) * 8 + i;
        int j = kk >> 6, c = kk & 63;
        v[i] = f2bf(w[o * 576 + c * 9 + j]);
    }
    *(bf16x8*)(W2 + (size_t)idx * 8) = v;
}

__global__ __launch_bounds__(256, 3)
void ta_main_kernel(const float* __restrict__ x, const short* __restrict__ W2,
                    const float* __restrict__ bias, float* __restrict__ out) {
    __shared__ short xs[ROWS * PITCH];              // 42,048 B, layout [tt][c], bf16

    const int tid  = threadIdx.x;
    const int wv   = tid >> 6;                      // wave 0..3 -> t-quadrant
    const int lane = tid & 63;
    const int l15  = lane & 15;
    const int quad = lane >> 4;
    const int b    = blockIdx.y;
    const int t0   = blockIdx.x * NT;

    // ---- stage x tile (transposed, fp32 -> bf16) ----
    const float* xb = x + ((size_t)(b * 64) << 16);
#pragma unroll 4
    for (int it = 0; it < 73; ++it) {
        unsigned item = (unsigned)(it * 256 + tid); // 73*256 = 64*292 exactly
        unsigned c  = item / 292u;
        unsigned tt = item - c * 292u;
        int tg = t0 - HALO + (int)tt;
        float v = 0.f;
        if ((unsigned)tg < (unsigned)T_LEN) v = xb[((size_t)c << 16) + (unsigned)tg];
        xs[tt * PITCH + c] = f2bf(v);
    }
    __syncthreads();

    // ---- K loop: 18 chunks of 32 (chunk ch: tap j = ch>>1, c-half h = ch&1) ----
    const int dtab[9] = {-17, -16, -15, -1, 0, 1, 15, 16, 17};
    f32x4 acc[4][4] = {};                           // [mt][nt]

#pragma unroll
    for (int ch = 0; ch < NCHUNK; ++ch) {
        const int j = ch >> 1, h = ch & 1;
        const int dd = dtab[j];
        bf16x8 a[4], bb[4];
#pragma unroll
        for (int mt = 0; mt < 4; ++mt)
            a[mt] = *(const bf16x8*)(W2 + (size_t)(((mt * NCHUNK + ch) * 64 + lane)) * 8);
#pragma unroll
        for (int nt = 0; nt < 4; ++nt) {
            int tl = wv * 64 + nt * 16 + l15;       // local t (n index)
            int tt = tl + HALO + dd;                // 0 .. 289
            bb[nt] = *(const bf16x8*)(xs + tt * PITCH + h * 32 + quad * 8);
        }
#pragma unroll
        for (int mt = 0; mt < 4; ++mt)
#pragma unroll
            for (int nt = 0; nt < 4; ++nt)
                acc[mt][nt] = __builtin_amdgcn_mfma_f32_16x16x32_bf16(a[mt], bb[nt], acc[mt][nt], 0, 0, 0);
    }

    // ---- epilogue: + bias, store fp32 ----
    // C/D layout (verified m89/m91): row(m) = quad*4 + r, col(n) = lane&15
#pragma unroll
    for (int mt = 0; mt < 4; ++mt) {
#pragma unroll
        for (int r = 0; r < 4; ++r) {
            int o = mt * 16 + quad * 4 + r;
            float bv = bias[o];
            size_t orow = ((size_t)((b << 6) + o)) << 16;
#pragma unroll
            for (int nt = 0; nt < 4; ++nt) {
                int t = t0 + wv * 64 + nt * 16 + l15;
                out[orow + t] = acc[mt][nt][r] + bv;
            }
        }
    }
}

extern "C" void kernel_launch(void* const* d_in, const int* in_sizes, int n_in,
                              void* d_out, int out_size, void* d_ws, size_t ws_size,
                              hipStream_t stream) {
    const float* x    = (const float*)d_in[0];
    const float* w    = (const float*)d_in[1];
    const float* bias = (const float*)d_in[2];
    float* out = (float*)d_out;
    short* W2  = (short*)d_ws;                      // needs 4*18*64*8*2 = 73,728 B

    hipLaunchKernelGGL(prep_w_kernel, dim3(18), dim3(256), 0, stream, w, W2);
    hipLaunchKernelGGL(ta_main_kernel, dim3(T_LEN / NT, 8), dim3(256), 0, stream,
                       x, W2, bias, out);
}

// Round 2
// 373.236 us; speedup vs baseline: 1.0039x; 1.0039x over previous
//
#include <hip/hip_runtime.h>

// TALayer: deformable 1D conv, fixed integer taps d[j] ∈ {-17,-16,-15,-1,0,1,15,16,17}
// out[b,o,t] = sum_{c,j} W[o,c,j] * x[b,c,t+d[j]] (zero-pad OOB) + bias[o]
// B=8, C=O=64, T=65536. bf16 MFMA GEMM: C[64, B*T] = W[64,576] * Xg[576, B*T].

typedef short bf16x8 __attribute__((ext_vector_type(8)));   // 8 bf16 (4 VGPRs)
typedef short bf16x4 __attribute__((ext_vector_type(4)));   // 4 bf16 (8 B, ds_read_b64)
typedef float f32x4  __attribute__((ext_vector_type(4)));   // MFMA accumulator

#define T_LEN   65536
#define NT      256           // t-tile per block
#define ROWS    296           // staged rows: global t in [t0-20, t0+276), float4-aligned
#define PITCH   68            // shorts per LDS row (136 B): 8B-aligned reads, conflict-free writes
#define LOFF    20            // x[t] lives at LDS row (t - t0 + 20)
#define NCHUNK  18            // K = 576 = 18 * 32

__device__ __forceinline__ short f2bf(float f) {
    union { float f; unsigned u; } v; v.f = f;
    unsigned u = v.u;
    u += 0x7fffu + ((u >> 16) & 1u);   // round-to-nearest-even
    return (short)(u >> 16);
}

// Weight -> MFMA A-fragment order (bf16), layout [ch][mt][lane][8]:
// W2[((ch*4 + mt)*64 + lane)*8 + i] = bf16(W[o = mt*16 + (lane&15)][kk = ch*32 + (lane>>4)*8 + i])
// kk = j*64 + c -> j = kk>>6, c = kk&63;  W strides [o][c][j] = (576, 9, 1).
__global__ void prep_w_kernel(const float* __restrict__ w, short* __restrict__ W2) {
    int idx = blockIdx.x * 256 + threadIdx.x;       // 0 .. 4607
    if (idx >= 4 * NCHUNK * 64) return;
    int lane = idx & 63;
    int g    = idx >> 6;            // ch*4 + mt
    int ch   = g >> 2;
    int mt   = g & 3;
    int o    = mt * 16 + (lane & 15);
    bf16x8 v;
#pragma unroll
    for (int i = 0; i < 8; ++i) {
        int kk = ch * 32 + (lane >> 4) * 8 + i;
        int j = kk >> 6, c = kk & 63;
        v[i] = f2bf(w[o * 576 + c * 9 + j]);
    }
    *(bf16x8*)(W2 + (size_t)idx * 8) = v;
}

__global__ __launch_bounds__(256, 4)
void ta_main_kernel(const float* __restrict__ x, const short* __restrict__ W2,
                    const float* __restrict__ bias, float* __restrict__ out) {
    __shared__ short xs[ROWS * PITCH];              // 40,256 B -> 4 blocks/CU

    const int tid  = threadIdx.x;
    const int wv   = tid >> 6;                      // wave -> t-quadrant
    const int lane = tid & 63;
    const int l15  = lane & 15;
    const int quad = lane >> 4;
    const int b    = blockIdx.y;
    const int t0   = blockIdx.x * NT;

    // ---- stage x tile: float4 loads, transpose to [tt][c] bf16 in LDS ----
    // thread (c = tid>>2, q = tid&3) loads float4 f = q + 4i, f < 74 (74*4 = 296 rows)
    const int c = tid >> 2;
    const int q = tid & 3;
    const float* xrow = x + (((size_t)(b * 64 + c)) << 16);
    const int tbase = t0 - LOFF;
    const bool interior = (t0 >= LOFF) && (t0 + (ROWS - LOFF) <= T_LEN);

#pragma unroll
    for (int i = 0; i < 19; ++i) {
        const int f = q + 4 * i;
        if (f < 74) {
            const int tt = 4 * f;
            const int tg = tbase + tt;
            float4 v;
            if (interior) {
                v = *(const float4*)(xrow + tg);
            } else {
                v.x = ((unsigned)(tg + 0) < (unsigned)T_LEN) ? xrow[tg + 0] : 0.f;
                v.y = ((unsigned)(tg + 1) < (unsigned)T_LEN) ? xrow[tg + 1] : 0.f;
                v.z = ((unsigned)(tg + 2) < (unsigned)T_LEN) ? xrow[tg + 2] : 0.f;
                v.w = ((unsigned)(tg + 3) < (unsigned)T_LEN) ? xrow[tg + 3] : 0.f;
            }
            xs[(tt + 0) * PITCH + c] = f2bf(v.x);
            xs[(tt + 1) * PITCH + c] = f2bf(v.y);
            xs[(tt + 2) * PITCH + c] = f2bf(v.z);
            xs[(tt + 3) * PITCH + c] = f2bf(v.w);
        }
    }
    __syncthreads();

    // ---- K loop: 18 chunks of 32 (chunk ch: tap j = ch>>1, c-half h = ch&1) ----
    // LDS row for (local t = tl, tap d) is tl + LOFF + d; bias base at tl+3 so
    // per-chunk deltas ((d+17)*PITCH + h*32) are non-negative compile-time consts.
    int bbase[4];
#pragma unroll
    for (int nt = 0; nt < 4; ++nt) {
        const int tl = wv * 64 + nt * 16 + l15;
        bbase[nt] = (tl + 3) * PITCH + quad * 8;    // shorts
    }
    const short* w2p = W2 + (size_t)lane * 8;

    f32x4 acc[4][4] = {};                           // [mt][nt]

#pragma unroll
    for (int ch = 0; ch < NCHUNK; ++ch) {
        const int dtab[9] = {-17, -16, -15, -1, 0, 1, 15, 16, 17};
        const int j = ch >> 1, h = ch & 1;
        const int roff = (dtab[j] + 17) * PITCH + h * 32;   // compile-time per chunk

        bf16x8 a[4], bb[4];
#pragma unroll
        for (int mt = 0; mt < 4; ++mt)
            a[mt] = *(const bf16x8*)(w2p + (size_t)(ch * 4 + mt) * 512);
#pragma unroll
        for (int nt = 0; nt < 4; ++nt) {
            union { bf16x8 v8; bf16x4 v4[2]; } u;
            u.v4[0] = *(const bf16x4*)(xs + bbase[nt] + roff);
            u.v4[1] = *(const bf16x4*)(xs + bbase[nt] + roff + 4);
            bb[nt] = u.v8;
        }
#pragma unroll
        for (int mt = 0; mt < 4; ++mt)
#pragma unroll
            for (int nt = 0; nt < 4; ++nt)
                acc[mt][nt] = __builtin_amdgcn_mfma_f32_16x16x32_bf16(a[mt], bb[nt], acc[mt][nt], 0, 0, 0);
    }

    // ---- epilogue: + bias, store fp32 ----
    // C/D layout: row(m) = quad*4 + r, col(n) = lane&15
#pragma unroll
    for (int mt = 0; mt < 4; ++mt) {
#pragma unroll
        for (int r = 0; r < 4; ++r) {
            const int o = mt * 16 + quad * 4 + r;
            const float bv = bias[o];
            const size_t orow = ((size_t)((b << 6) + o)) << 16;
#pragma unroll
            for (int nt = 0; nt < 4; ++nt) {
                const int t = t0 + wv * 64 + nt * 16 + l15;
                out[orow + t] = acc[mt][nt][r] + bv;
            }
        }
    }
}

extern "C" void kernel_launch(void* const* d_in, const int* in_sizes, int n_in,
                              void* d_out, int out_size, void* d_ws, size_t ws_size,
                              hipStream_t stream) {
    const float* x    = (const float*)d_in[0];
    const float* w    = (const float*)d_in[1];
    const float* bias = (const float*)d_in[2];
    float* out = (float*)d_out;
    short* W2  = (short*)d_ws;                      // 4*18*64*8*2 = 73,728 B

    hipLaunchKernelGGL(prep_w_kernel, dim3(18), dim3(256), 0, stream, w, W2);
    hipLaunchKernelGGL(ta_main_kernel, dim3(T_LEN / NT, 8), dim3(256), 0, stream,
                       x, W2, bias, out);
}

// Round 4
// 364.127 us; speedup vs baseline: 1.0290x; 1.0250x over previous
//
#include <hip/hip_runtime.h>

// TALayer: deformable 1D conv, fixed integer taps d[j] ∈ {-17,-16,-15,-1,0,1,15,16,17}
// out[b,o,t] = sum_{c,j} W[o,c,j] * x[b,c,t+d[j]] (zero-pad OOB) + bias[o]
// B=8, C=O=64, T=65536. bf16 MFMA GEMM: C[64, B*T] = W[64,576] * Xg[576, B*T].
// R4: LDS-transposed epilogue -> each wave store = 1 KB contiguous (full lines).
//     (R3 fix: nontemporal store must use clang ext_vector, not HIP float4 class)

typedef short bf16x8 __attribute__((ext_vector_type(8)));   // 8 bf16 (4 VGPRs)
typedef short bf16x4 __attribute__((ext_vector_type(4)));   // 4 bf16 (8 B, ds_read_b64)
typedef float f32x4  __attribute__((ext_vector_type(4)));   // MFMA accumulator / 16B vec

#define T_LEN   65536
#define NT      256           // t-tile per block
#define ROWS    296           // staged rows: global t in [t0-20, t0+276)
#define PITCH   68            // shorts per LDS row (136 B)
#define LOFF    20            // x[t] -> LDS row (t - t0 + 20)
#define NCHUNK  18            // K = 576 = 18 * 32
#define OPITCH  260           // floats per epilogue LDS row (260 = 4*65, 16B-aligned rows)
#define SMEM_BYTES (ROWS * PITCH * 2)   // 40,256 B -> 4 blocks/CU

__device__ __forceinline__ short f2bf(float f) {
    union { float f; unsigned u; } v; v.f = f;
    unsigned u = v.u;
    u += 0x7fffu + ((u >> 16) & 1u);   // round-to-nearest-even
    return (short)(u >> 16);
}

// Weight -> MFMA A-fragment order (bf16), layout [ch][mt][lane][8]:
// W2[((ch*4 + mt)*64 + lane)*8 + i] = bf16(W[o = mt*16 + (lane&15)][kk = ch*32 + (lane>>4)*8 + i])
// kk = j*64 + c -> j = kk>>6, c = kk&63;  W strides [o][c][j] = (576, 9, 1).
__global__ void prep_w_kernel(const float* __restrict__ w, short* __restrict__ W2) {
    int idx = blockIdx.x * 256 + threadIdx.x;       // 0 .. 4607
    if (idx >= 4 * NCHUNK * 64) return;
    int lane = idx & 63;
    int g    = idx >> 6;            // ch*4 + mt
    int ch   = g >> 2;
    int mt   = g & 3;
    int o    = mt * 16 + (lane & 15);
    bf16x8 v;
#pragma unroll
    for (int i = 0; i < 8; ++i) {
        int kk = ch * 32 + (lane >> 4) * 8 + i;
        int j = kk >> 6, c = kk & 63;
        v[i] = f2bf(w[o * 576 + c * 9 + j]);
    }
    *(bf16x8*)(W2 + (size_t)idx * 8) = v;
}

__global__ __launch_bounds__(256, 4)
void ta_main_kernel(const float* __restrict__ x, const short* __restrict__ W2,
                    const float* __restrict__ bias, float* __restrict__ out) {
    __shared__ __align__(16) char smem[SMEM_BYTES];
    short* xs = (short*)smem;                       // staging: [tt][c] bf16, pitch 68
    float* os = (float*)smem;                       // epilogue: [o_local][t] f32, pitch 260

    const int tid  = threadIdx.x;
    const int wv   = tid >> 6;                      // wave -> t-quadrant
    const int lane = tid & 63;
    const int l15  = lane & 15;
    const int quad = lane >> 4;
    const int b    = blockIdx.y;
    const int t0   = blockIdx.x * NT;

    // ---- stage x tile: float4 loads, transpose to [tt][c] bf16 in LDS ----
    const int c = tid >> 2;
    const int q = tid & 3;
    const float* xrow = x + (((size_t)(b * 64 + c)) << 16);
    const int tbase = t0 - LOFF;
    const bool interior = (t0 >= LOFF) && (t0 + (ROWS - LOFF) <= T_LEN);

#pragma unroll
    for (int i = 0; i < 19; ++i) {
        const int f = q + 4 * i;
        if (f < 74) {
            const int tt = 4 * f;
            const int tg = tbase + tt;
            f32x4 v;
            if (interior) {
                v = *(const f32x4*)(xrow + tg);
            } else {
                v[0] = ((unsigned)(tg + 0) < (unsigned)T_LEN) ? xrow[tg + 0] : 0.f;
                v[1] = ((unsigned)(tg + 1) < (unsigned)T_LEN) ? xrow[tg + 1] : 0.f;
                v[2] = ((unsigned)(tg + 2) < (unsigned)T_LEN) ? xrow[tg + 2] : 0.f;
                v[3] = ((unsigned)(tg + 3) < (unsigned)T_LEN) ? xrow[tg + 3] : 0.f;
            }
            xs[(tt + 0) * PITCH + c] = f2bf(v[0]);
            xs[(tt + 1) * PITCH + c] = f2bf(v[1]);
            xs[(tt + 2) * PITCH + c] = f2bf(v[2]);
            xs[(tt + 3) * PITCH + c] = f2bf(v[3]);
        }
    }
    __syncthreads();

    // ---- K loop: 18 chunks of 32 (chunk ch: tap j = ch>>1, c-half h = ch&1) ----
    int bbase[4];
#pragma unroll
    for (int nt = 0; nt < 4; ++nt) {
        const int tl = wv * 64 + nt * 16 + l15;
        bbase[nt] = (tl + 3) * PITCH + quad * 8;    // shorts; +3 so roff >= 0
    }
    const short* w2p = W2 + (size_t)lane * 8;

    f32x4 acc[4][4] = {};                           // [mt][nt]

#pragma unroll
    for (int ch = 0; ch < NCHUNK; ++ch) {
        const int dtab[9] = {-17, -16, -15, -1, 0, 1, 15, 16, 17};
        const int j = ch >> 1, h = ch & 1;
        const int roff = (dtab[j] + 17) * PITCH + h * 32;   // compile-time per chunk

        bf16x8 a[4], bb[4];
#pragma unroll
        for (int mt = 0; mt < 4; ++mt)
            a[mt] = *(const bf16x8*)(w2p + (size_t)(ch * 4 + mt) * 512);
#pragma unroll
        for (int nt = 0; nt < 4; ++nt) {
            union { bf16x8 v8; bf16x4 v4[2]; } u;
            u.v4[0] = *(const bf16x4*)(xs + bbase[nt] + roff);
            u.v4[1] = *(const bf16x4*)(xs + bbase[nt] + roff + 4);
            bb[nt] = u.v8;
        }
#pragma unroll
        for (int mt = 0; mt < 4; ++mt)
#pragma unroll
            for (int nt = 0; nt < 4; ++nt)
                acc[mt][nt] = __builtin_amdgcn_mfma_f32_16x16x32_bf16(a[mt], bb[nt], acc[mt][nt], 0, 0, 0);
    }

    // ---- epilogue: round-trip through LDS so each wave writes full contiguous lines ----
    // C/D layout: row(m) = quad*4 + r, col(n) = lane&15
    // Two passes (o in [0,32) then [32,64)), each: acc -> LDS [o_local][t] -> 1KB/wave stores.
    const size_t outb = ((size_t)(b * 64)) << 16;
#pragma unroll
    for (int p = 0; p < 2; ++p) {
        __syncthreads();                            // xs reads (p=0) / os reads (p=1) done
#pragma unroll
        for (int mtl = 0; mtl < 2; ++mtl) {
            const int mt = 2 * p + mtl;
#pragma unroll
            for (int r = 0; r < 4; ++r) {
                const int ol = mtl * 16 + quad * 4 + r;           // 0..31
                const float bv = bias[mt * 16 + quad * 4 + r];
#pragma unroll
                for (int nt = 0; nt < 4; ++nt) {
                    const int t = wv * 64 + nt * 16 + l15;
                    os[ol * OPITCH + t] = acc[mt][nt][r] + bv;    // 2-way bank: free
                }
            }
        }
        __syncthreads();
        // read back + store: item = [o_local][f4], 32*64 items; wave = one full row KB
#pragma unroll
        for (int i = 0; i < 8; ++i) {
            const int item = tid + 256 * i;         // 0..2047
            const int ol = item >> 6;               // 0..31
            const int f4 = item & 63;               // 0..63
            const f32x4 v = *(const f32x4*)(os + ol * OPITCH + 4 * f4);
            const int o = p * 32 + ol;
            __builtin_nontemporal_store(v, (f32x4*)(out + outb + (((size_t)o) << 16) + t0 + 4 * f4));
        }
    }
}

extern "C" void kernel_launch(void* const* d_in, const int* in_sizes, int n_in,
                              void* d_out, int out_size, void* d_ws, size_t ws_size,
                              hipStream_t stream) {
    const float* x    = (const float*)d_in[0];
    const float* w    = (const float*)d_in[1];
    const float* bias = (const float*)d_in[2];
    float* out = (float*)d_out;
    short* W2  = (short*)d_ws;                      // 4*18*64*8*2 = 73,728 B

    hipLaunchKernelGGL(prep_w_kernel, dim3(18), dim3(256), 0, stream, w, W2);
    hipLaunchKernelGGL(ta_main_kernel, dim3(T_LEN / NT, 8), dim3(256), 0, stream,
                       x, W2, bias, out);
}